// Round 5
// baseline (682.020 us; speedup 1.0000x reference)
//
#include <hip/hip_runtime.h>

typedef __bf16 bf16;
typedef bf16 bf16x2 __attribute__((ext_vector_type(2)));
typedef bf16 bf16x8 __attribute__((ext_vector_type(8)));
typedef float f32x4 __attribute__((ext_vector_type(4)));
typedef unsigned int u32;
typedef unsigned short u16;

#define BB 4
#define SS 4096
#define DD 1024
#define EE 64
static constexpr float SCALE2 = 0.18033688011112042f; // (1/8)*log2(e)
static constexpr float MFIX = 16.0f;                  // fixed softmax shift (log2 domain)

#define MFMA(a,b,c) __builtin_amdgcn_mfma_f32_16x16x32_bf16((a),(b),(c),0,0,0)

typedef __attribute__((address_space(3))) unsigned int lds_u32;
typedef const __attribute__((address_space(1))) unsigned int glb_u32;

static __device__ __forceinline__ void gload16(const void* g, void* l) {
    __builtin_amdgcn_global_load_lds((glb_u32*)g, (lds_u32*)l, 16, 0, 0);
}

static __device__ __forceinline__ u16 f2bf(float x) {
    union { bf16 h; u16 u; } v; v.h = (bf16)x;
    return v.u;
}
static __device__ __forceinline__ u32 pk2(float a, float b) {
    bf16x2 t; t[0] = (bf16)a; t[1] = (bf16)b;
    return __builtin_bit_cast(u32, t);
}
static __device__ __forceinline__ float fexp2(float x) {
    return __builtin_amdgcn_exp2f(x);
}

// ---------------- Kernel 1: SINGLE-PASS prep (unchanged — verified) ----------
__global__ __launch_bounds__(512, 2) void k_prep(const float* __restrict__ enc,
                                                 const float* __restrict__ wq,
                                                 const float* __restrict__ wk,
                                                 u16* __restrict__ qout,
                                                 u16* __restrict__ kout,
                                                 u16* __restrict__ vt) {
    __shared__ __align__(16) u16 la[4096];
    __shared__ __align__(16) u16 lw[8192];
    __shared__ __align__(16) u32 lt[2144];
    const int tid = threadIdx.x;
    const int m0 = blockIdx.x * 64;
    const int bb = m0 >> 12, s0 = m0 & 4095;
    const int w = tid >> 6, lane = tid & 63, l15 = lane & 15, quad = lane >> 4;
    const int ari = tid >> 3, ag = tid & 7;
    const int wri = tid >> 2, wg = (tid & 3) * 2;
    const float* arow = enc + (size_t)(m0 + ari) * DD + ag * 8;
    const float* wrow = ((wri < 64) ? (wq + (size_t)wri * DD) : (wk + (size_t)(wri - 64) * DD)) + (tid & 3) * 16;
    const int tdp = tid >> 3, toct = tid & 7;
    u16* vdst = vt + ((size_t)(bb * DD + 2 * tdp)) * SS + s0 + toct * 8;

    float4 a0 = *(const float4*)(arow);
    float4 a1 = *(const float4*)(arow + 4);
    float4 b0 = *(const float4*)(wrow);
    float4 b1 = *(const float4*)(wrow + 4);
    float4 b2 = *(const float4*)(wrow + 8);
    float4 b3 = *(const float4*)(wrow + 12);

    f32x4 acc[4];
#pragma unroll
    for (int i = 0; i < 4; i++) acc[i] = f32x4{0.f, 0.f, 0.f, 0.f};

    for (int kk = 0; kk < DD; kk += 64) {
        uint4 pa, pw0, pw1;
        pa.x = pk2(a0.x, a0.y); pa.y = pk2(a0.z, a0.w);
        pa.z = pk2(a1.x, a1.y); pa.w = pk2(a1.z, a1.w);
        pw0.x = pk2(b0.x, b0.y); pw0.y = pk2(b0.z, b0.w);
        pw0.z = pk2(b1.x, b1.y); pw0.w = pk2(b1.z, b1.w);
        pw1.x = pk2(b2.x, b2.y); pw1.y = pk2(b2.z, b2.w);
        pw1.z = pk2(b3.x, b3.y); pw1.w = pk2(b3.z, b3.w);
        __syncthreads();
        *(uint4*)&la[ari * 64 + (ag ^ (ari & 7)) * 8] = pa;
        *(uint4*)&lw[wri * 64 + ((wg + 0) ^ (wri & 7)) * 8] = pw0;
        *(uint4*)&lw[wri * 64 + ((wg + 1) ^ (wri & 7)) * 8] = pw1;
        lt[(ag * 4 + 0) * 67 + ari] = pa.x;
        lt[(ag * 4 + 1) * 67 + ari] = pa.y;
        lt[(ag * 4 + 2) * 67 + ari] = pa.z;
        lt[(ag * 4 + 3) * 67 + ari] = pa.w;
        __syncthreads();
        if (kk + 64 < DD) {
            a0 = *(const float4*)(arow + kk + 64);
            a1 = *(const float4*)(arow + kk + 68);
            b0 = *(const float4*)(wrow + kk + 64);
            b1 = *(const float4*)(wrow + kk + 68);
            b2 = *(const float4*)(wrow + kk + 72);
            b3 = *(const float4*)(wrow + kk + 76);
        }
        int m = 16 * (w & 3) + l15;
#pragma unroll
        for (int es = 0; es < 2; es++) {
            bf16x8 af = *(const bf16x8*)&la[m * 64 + ((((es << 2) + quad) ^ (m & 7))) * 8];
#pragma unroll
            for (int ct = 0; ct < 4; ct++) {
                int n = 64 * (w >> 2) + 16 * ct + l15;
                bf16x8 bf_ = *(const bf16x8*)&lw[n * 64 + ((((es << 2) + quad) ^ (n & 7))) * 8];
                acc[ct] = MFMA(af, bf_, acc[ct]);
            }
        }
        if (tid < 256) {
            u32 a_[8];
#pragma unroll
            for (int j = 0; j < 8; j++) a_[j] = lt[tdp * 67 + toct * 8 + j];
            uint4 r0, r1;
            r0.x = (a_[0] & 0xffffu) | (a_[1] << 16);
            r0.y = (a_[2] & 0xffffu) | (a_[3] << 16);
            r0.z = (a_[4] & 0xffffu) | (a_[5] << 16);
            r0.w = (a_[6] & 0xffffu) | (a_[7] << 16);
            r1.x = (a_[0] >> 16) | (a_[1] & 0xffff0000u);
            r1.y = (a_[2] >> 16) | (a_[3] & 0xffff0000u);
            r1.z = (a_[4] >> 16) | (a_[5] & 0xffff0000u);
            r1.w = (a_[6] >> 16) | (a_[7] & 0xffff0000u);
            u16* dst = vdst + (size_t)kk * SS;
            *(uint4*)dst = r0;
            *(uint4*)(dst + SS) = r1;
        }
    }
#pragma unroll
    for (int ct = 0; ct < 4; ct++) {
        int n = 64 * (w >> 2) + 16 * ct + l15;
        u16* dst = (n < 64) ? qout : kout;
        int col = n & 63;
#pragma unroll
        for (int r = 0; r < 4; r++) {
            int grow = m0 + 16 * (w & 3) + 4 * quad + r;
            dst[(size_t)grow * EE + col] = f2bf(acc[ct][r]);
        }
    }
}

// ---------------- Kernel 2: attention v3 -- q128 merged-phase, V straight from L2 ----
// Synthesis of R0 (q128 density: 40 MFMA/wave-phase hides latency) and R4's validated
// mechanisms (V-from-L2 + XCD decode -> FETCH 199->29.6 MB). vs R0:
//  * lv/gv deleted: no V LDS round-trip. LDS 115200 -> 49664 B => 2 blocks/CU
//    (4 waves/SIMD, 2x TLP). ~96 of ~160 b128-equiv LDS ops/block-phase removed.
//  * vb fragments loaded from global (L2) at TOP of phase; pass A's 8 MFMA + 16 exp2
//    runs between issue and pass-B use -> L2 latency covered in-wave, plus 2x waves.
//  * XCD-aware decode (proven in R4): 2 combos/XCD, vt slabs L2-resident.
// LDS (u16 idx): lp[2] @0/8192 (16KB each); lsum @16384; lk[2] @16640/20736 (8KB each).
__global__ __launch_bounds__(512, 4) void k_attn(const u16* __restrict__ qg, const u16* __restrict__ kg,
                                                 const u16* __restrict__ vt, float* __restrict__ out) {
    __shared__ __align__(16) u16 lds[24832];   // 49664 B -> 2 blocks/CU
    float* lsum = (float*)&lds[16384];
    const int tid = threadIdx.x;
    const int w = tid >> 6, lane = tid & 63, l15 = lane & 15, quad = lane >> 4;
    // XCD-aware decode (R4-proven): 256 blocks, phys round-robin over 8 XCDs.
    const int xcd = blockIdx.x & 7;
    const int idx = blockIdx.x >> 3;            // [0,32)
    const int pr = idx & 15;                    // q-tile pair selector
    const int combo = xcd * 2 + (idx >> 4);     // [0,16): 2 combos per XCD
    const int ds = combo & 3, b = combo >> 2;
    const int d0 = ds * 256;
    const int kr = w & 1, qc = w >> 1;   // pass A: 2 k-halves x 4 q-slices(32)
    const int dc = w & 3, qr = w >> 2;   // pass B: 4 d-slices(64) x 2 q-halves(64)
    const u16* kbase = kg + (size_t)b * SS * EE;
    const u16* vbase = vt + ((size_t)b * DD + d0) * SS;
    const int kgrow = tid >> 3, kglog = (tid & 7) ^ (kgrow & 7);
    const u16* kptr = kbase + (size_t)kgrow * EE + kglog * 8;
    // per-ct vt row pointers for PV B-fragments (quad lanes at same l15 share a 64B line)
    const u16* vrow[4];
#pragma unroll
    for (int ct = 0; ct < 4; ct++)
        vrow[ct] = vbase + (size_t)(64 * dc + 16 * ct + l15) * SS + quad * 8;

    for (int half = 0; half < 2; half++) {
        const int qt = half ? pr : (31 - pr);   // heavy tile first; pair sums to 70 phases
        const int q0 = qt * 128;
        const int KT = 2 * qt + 2;
        const u16* qbase = qg + ((size_t)b * SS + q0) * EE;
        __syncthreads();   // prior half fully done with all LDS regions
        if (tid < 128) lsum[tid] = 0.f;
        gload16(kptr, (void*)&lds[16640 + tid * 8]);   // K tile 0 -> lk[0]
        bf16x8 qf[2][2];
#pragma unroll
        for (int ct = 0; ct < 2; ct++) {
            int qv = 32 * qc + 16 * ct + l15;
#pragma unroll
            for (int es = 0; es < 2; es++)
                qf[ct][es] = *(const bf16x8*)(qbase + (size_t)qv * EE + es * 32 + quad * 8);
        }
        f32x4 o[4][4];
#pragma unroll
        for (int i = 0; i < 4; i++)
#pragma unroll
            for (int j = 0; j < 4; j++) o[i][j] = f32x4{0.f, 0.f, 0.f, 0.f};
        float rl[2] = {0.f, 0.f};
        __syncthreads();   // prologue staging drained, lsum zeros visible

        for (int p = 0; p <= KT; p++) {
            // ---- issue V fragments for pass B(p-1) FIRST (L2 loads; consumed at phase end)
            bf16x8 vbt[2][4];
            if (p >= 1) {
                const int k0b = (p - 1) * 64;
#pragma unroll
                for (int ks = 0; ks < 2; ks++)
#pragma unroll
                    for (int ct = 0; ct < 4; ct++)
                        vbt[ks][ct] = *(const bf16x8*)(vrow[ct] + k0b + ks * 32);
            }
            // ---- K prefetch for tile p+1 (LDS-DMA, alt slot; drained at phase barrier)
            if (p + 1 < KT)
                gload16(kptr + (size_t)(p + 1) * 64 * EE,
                        (void*)&lds[16640 + ((p + 1) & 1) * 4096 + tid * 8]);
            // ---- pass A(p): S^T (64k x 128q), exp2, P -> lp[p&1] ----
            if (p < KT) {
                const int k0 = p * 64;
                const u16* lk = &lds[16640 + (p & 1) * 4096];
                u16* lpw = &lds[(p & 1) * 8192];
                const bool dg = (p >= KT - 2);
#pragma unroll
                for (int rt = 0; rt < 2; rt++) {
                    int m = 32 * kr + 16 * rt + l15;
                    bf16x8 ka0 = *(const bf16x8*)&lk[m * 64 + ((quad ^ (m & 7))) * 8];
                    bf16x8 ka1 = *(const bf16x8*)&lk[m * 64 + (((4 + quad) ^ (m & 7))) * 8];
#pragma unroll
                    for (int ct = 0; ct < 2; ct++) {
                        f32x4 c = f32x4{0.f, 0.f, 0.f, 0.f};
                        c = MFMA(ka0, qf[ct][0], c);
                        c = MFMA(ka1, qf[ct][1], c);
                        int qv = 32 * qc + 16 * ct + l15;
                        float pv[4];
#pragma unroll
                        for (int r = 0; r < 4; r++) {
                            float arg = __builtin_fmaf(c[r], SCALE2, -MFIX);
                            if (dg) {
                                int kp = k0 + 32 * kr + 16 * rt + 4 * quad + r;
                                if (kp > q0 + qv) arg = -3.0e38f;   // exp2 -> 0
                            }
                            pv[r] = fexp2(arg);
                        }
                        rl[ct] += (pv[0] + pv[1]) + (pv[2] + pv[3]);
                        int g16 = 4 * kr + 2 * rt + (quad >> 1);
                        uint2 pkk;
                        pkk.x = pk2(pv[0], pv[1]);
                        pkk.y = pk2(pv[2], pv[3]);
                        *(uint2*)&lpw[qv * 64 + (g16 ^ (qv & 7)) * 8 + (quad & 1) * 4] = pkk;
                    }
                }
            }
            // ---- pass B(p-1): O += P * Vt ; P from lp[(p-1)&1], V from vbt regs ----
            if (p >= 1) {
                const u16* lpr = &lds[((p - 1) & 1) * 8192];
#pragma unroll
                for (int ks = 0; ks < 2; ks++) {
                    bf16x8 pa[4];
#pragma unroll
                    for (int rt = 0; rt < 4; rt++) {
                        int m = 64 * qr + 16 * rt + l15;
                        pa[rt] = *(const bf16x8*)&lpr[m * 64 + ((((ks << 2) + quad) ^ (m & 7))) * 8];
                    }
                    __builtin_amdgcn_s_setprio(1);
#pragma unroll
                    for (int rt = 0; rt < 4; rt++)
#pragma unroll
                        for (int ct = 0; ct < 4; ct++)
                            o[rt][ct] = MFMA(pa[rt], vbt[ks][ct], o[rt][ct]);
                    __builtin_amdgcn_s_setprio(0);
                }
            }
            __syncthreads();   // single barrier per phase
        }
        // ---- denominator ----
#pragma unroll
        for (int ct = 0; ct < 2; ct++) {
            float t = rl[ct];
            t += __shfl_xor(t, 16, 64);
            t += __shfl_xor(t, 32, 64);
            if (quad == 0) atomicAdd(&lsum[32 * qc + 16 * ct + l15], t);
        }
        __syncthreads();
        // ---- epilogue ----
        float* obase = out + ((size_t)b * SS + q0) * DD + d0 + dc * 64;
#pragma unroll
        for (int rt = 0; rt < 4; rt++) {
#pragma unroll
            for (int r = 0; r < 4; r++) {
                int row = 64 * qr + 16 * rt + 4 * quad + r;
                float li = 1.0f / lsum[row];
#pragma unroll
                for (int ct = 0; ct < 4; ct++)
                    obase[(size_t)row * DD + ct * 16 + l15] = o[rt][ct][r] * li;
            }
        }
    }
}

extern "C" void kernel_launch(void* const* d_in, const int* in_sizes, int n_in,
                              void* d_out, int out_size, void* d_ws, size_t ws_size,
                              hipStream_t stream) {
    (void)in_sizes; (void)n_in; (void)out_size; (void)ws_size;
    const float* enc = (const float*)d_in[0];
    const float* wq = (const float*)d_in[1];
    const float* wk = (const float*)d_in[2];
    char* ws = (char*)d_ws;
    u16* qbf = (u16*)ws;                  // 2 MiB
    u16* kbf = (u16*)(ws + (2ull << 20)); // 2 MiB
    u16* vt  = (u16*)(ws + (4ull << 20)); // 32 MiB
    float* out = (float*)d_out;

    hipLaunchKernelGGL(k_prep, dim3(256), dim3(512), 0, stream, enc, wq, wk, qbf, kbf, vt);
    hipLaunchKernelGGL(k_attn, dim3(256), dim3(512), 0, stream, qbf, kbf, vt, out);
}

// Round 7
// 280.606 us; speedup vs baseline: 2.4305x; 2.4305x over previous
//
#include <hip/hip_runtime.h>

typedef __bf16 bf16;
typedef bf16 bf16x2 __attribute__((ext_vector_type(2)));
typedef bf16 bf16x8 __attribute__((ext_vector_type(8)));
typedef float f32x4 __attribute__((ext_vector_type(4)));
typedef unsigned int u32;
typedef unsigned short u16;

#define BB 4
#define SS 4096
#define DD 1024
#define EE 64
static constexpr float SCALE2 = 0.18033688011112042f; // (1/8)*log2(e)
static constexpr float MFIX = 16.0f;                  // fixed softmax shift (log2 domain)

#define MFMA(a,b,c) __builtin_amdgcn_mfma_f32_16x16x32_bf16((a),(b),(c),0,0,0)

typedef __attribute__((address_space(3))) unsigned int lds_u32;
typedef const __attribute__((address_space(1))) unsigned int glb_u32;

static __device__ __forceinline__ void gload16(const void* g, void* l) {
    __builtin_amdgcn_global_load_lds((glb_u32*)g, (lds_u32*)l, 16, 0, 0);
}

static __device__ __forceinline__ u16 f2bf(float x) {
    union { bf16 h; u16 u; } v; v.h = (bf16)x;
    return v.u;
}
static __device__ __forceinline__ u32 pk2(float a, float b) {
    bf16x2 t; t[0] = (bf16)a; t[1] = (bf16)b;
    return __builtin_bit_cast(u32, t);
}
static __device__ __forceinline__ float fexp2(float x) {
    return __builtin_amdgcn_exp2f(x);
}

// ---------------- Kernel 1: SINGLE-PASS prep (unchanged — verified) ----------
__global__ __launch_bounds__(512, 2) void k_prep(const float* __restrict__ enc,
                                                 const float* __restrict__ wq,
                                                 const float* __restrict__ wk,
                                                 u16* __restrict__ qout,
                                                 u16* __restrict__ kout,
                                                 u16* __restrict__ vt) {
    __shared__ __align__(16) u16 la[4096];
    __shared__ __align__(16) u16 lw[8192];
    __shared__ __align__(16) u32 lt[2144];
    const int tid = threadIdx.x;
    const int m0 = blockIdx.x * 64;
    const int bb = m0 >> 12, s0 = m0 & 4095;
    const int w = tid >> 6, lane = tid & 63, l15 = lane & 15, quad = lane >> 4;
    const int ari = tid >> 3, ag = tid & 7;
    const int wri = tid >> 2, wg = (tid & 3) * 2;
    const float* arow = enc + (size_t)(m0 + ari) * DD + ag * 8;
    const float* wrow = ((wri < 64) ? (wq + (size_t)wri * DD) : (wk + (size_t)(wri - 64) * DD)) + (tid & 3) * 16;
    const int tdp = tid >> 3, toct = tid & 7;
    u16* vdst = vt + ((size_t)(bb * DD + 2 * tdp)) * SS + s0 + toct * 8;

    float4 a0 = *(const float4*)(arow);
    float4 a1 = *(const float4*)(arow + 4);
    float4 b0 = *(const float4*)(wrow);
    float4 b1 = *(const float4*)(wrow + 4);
    float4 b2 = *(const float4*)(wrow + 8);
    float4 b3 = *(const float4*)(wrow + 12);

    f32x4 acc[4];
#pragma unroll
    for (int i = 0; i < 4; i++) acc[i] = f32x4{0.f, 0.f, 0.f, 0.f};

    for (int kk = 0; kk < DD; kk += 64) {
        uint4 pa, pw0, pw1;
        pa.x = pk2(a0.x, a0.y); pa.y = pk2(a0.z, a0.w);
        pa.z = pk2(a1.x, a1.y); pa.w = pk2(a1.z, a1.w);
        pw0.x = pk2(b0.x, b0.y); pw0.y = pk2(b0.z, b0.w);
        pw0.z = pk2(b1.x, b1.y); pw0.w = pk2(b1.z, b1.w);
        pw1.x = pk2(b2.x, b2.y); pw1.y = pk2(b2.z, b2.w);
        pw1.z = pk2(b3.x, b3.y); pw1.w = pk2(b3.z, b3.w);
        __syncthreads();
        *(uint4*)&la[ari * 64 + (ag ^ (ari & 7)) * 8] = pa;
        *(uint4*)&lw[wri * 64 + ((wg + 0) ^ (wri & 7)) * 8] = pw0;
        *(uint4*)&lw[wri * 64 + ((wg + 1) ^ (wri & 7)) * 8] = pw1;
        lt[(ag * 4 + 0) * 67 + ari] = pa.x;
        lt[(ag * 4 + 1) * 67 + ari] = pa.y;
        lt[(ag * 4 + 2) * 67 + ari] = pa.z;
        lt[(ag * 4 + 3) * 67 + ari] = pa.w;
        __syncthreads();
        if (kk + 64 < DD) {
            a0 = *(const float4*)(arow + kk + 64);
            a1 = *(const float4*)(arow + kk + 68);
            b0 = *(const float4*)(wrow + kk + 64);
            b1 = *(const float4*)(wrow + kk + 68);
            b2 = *(const float4*)(wrow + kk + 72);
            b3 = *(const float4*)(wrow + kk + 76);
        }
        int m = 16 * (w & 3) + l15;
#pragma unroll
        for (int es = 0; es < 2; es++) {
            bf16x8 af = *(const bf16x8*)&la[m * 64 + ((((es << 2) + quad) ^ (m & 7))) * 8];
#pragma unroll
            for (int ct = 0; ct < 4; ct++) {
                int n = 64 * (w >> 2) + 16 * ct + l15;
                bf16x8 bf_ = *(const bf16x8*)&lw[n * 64 + ((((es << 2) + quad) ^ (n & 7))) * 8];
                acc[ct] = MFMA(af, bf_, acc[ct]);
            }
        }
        if (tid < 256) {
            u32 a_[8];
#pragma unroll
            for (int j = 0; j < 8; j++) a_[j] = lt[tdp * 67 + toct * 8 + j];
            uint4 r0, r1;
            r0.x = (a_[0] & 0xffffu) | (a_[1] << 16);
            r0.y = (a_[2] & 0xffffu) | (a_[3] << 16);
            r0.z = (a_[4] & 0xffffu) | (a_[5] << 16);
            r0.w = (a_[6] & 0xffffu) | (a_[7] << 16);
            r1.x = (a_[0] >> 16) | (a_[1] & 0xffff0000u);
            r1.y = (a_[2] >> 16) | (a_[3] & 0xffff0000u);
            r1.z = (a_[4] >> 16) | (a_[5] & 0xffff0000u);
            r1.w = (a_[6] >> 16) | (a_[7] & 0xffff0000u);
            u16* dst = vdst + (size_t)kk * SS;
            *(uint4*)dst = r0;
            *(uint4*)(dst + SS) = r1;
        }
    }
#pragma unroll
    for (int ct = 0; ct < 4; ct++) {
        int n = 64 * (w >> 2) + 16 * ct + l15;
        u16* dst = (n < 64) ? qout : kout;
        int col = n & 63;
#pragma unroll
        for (int r = 0; r < 4; r++) {
            int grow = m0 + 16 * (w & 3) + 4 * quad + r;
            dst[(size_t)grow * EE + col] = f2bf(acc[ct][r]);
        }
    }
}

// ---------------- Kernel 2: attention v3b -- q128 merged-phase, V from L2, spill-free
// R5 post-mortem: launch_bounds(512,4) empirically caps VGPR at 64 on this toolchain
// (R4/R5 both measured 64) -> q128 state (~150 regs) spilled to scratch: WRITE 65MB ->
// 1.05GB, dur 570us. Fix:
//  * launch_bounds(512,2): 128-VGPR cap (R0 measured 124). LDS 49.6KB + VGPR<=128
//    still yields 2 blocks/CU (4 waves/SIMD).
//  * V prefetch split: ks=0 fragments (16 regs) at top of phase; ks=1 issued inside
//    pass B covered by ks=0's 16 MFMAs -> peak live V-regs during pass A is 16.
// LDS (u16 idx): lp[2] @0/8192 (16KB each); lsum @16384; lk[2] @16640/20736 (8KB each).
__global__ __launch_bounds__(512, 2) void k_attn(const u16* __restrict__ qg, const u16* __restrict__ kg,
                                                 const u16* __restrict__ vt, float* __restrict__ out) {
    __shared__ __align__(16) u16 lds[24832];   // 49664 B -> 2 blocks/CU
    float* lsum = (float*)&lds[16384];
    const int tid = threadIdx.x;
    const int w = tid >> 6, lane = tid & 63, l15 = lane & 15, quad = lane >> 4;
    // XCD-aware decode (R4-proven: FETCH 199->29.6MB): 256 blocks, round-robin XCDs.
    const int xcd = blockIdx.x & 7;
    const int idx = blockIdx.x >> 3;            // [0,32)
    const int pr = idx & 15;                    // q-tile pair selector
    const int combo = xcd * 2 + (idx >> 4);     // [0,16): 2 combos per XCD
    const int ds = combo & 3, b = combo >> 2;
    const int d0 = ds * 256;
    const int kr = w & 1, qc = w >> 1;   // pass A: 2 k-halves x 4 q-slices(32)
    const int dc = w & 3, qr = w >> 2;   // pass B: 4 d-slices(64) x 2 q-halves(64)
    const u16* kbase = kg + (size_t)b * SS * EE;
    const u16* vbase = vt + ((size_t)b * DD + d0) * SS;
    const int kgrow = tid >> 3, kglog = (tid & 7) ^ (kgrow & 7);
    const u16* kptr = kbase + (size_t)kgrow * EE + kglog * 8;
    // per-ct vt row pointers for PV B-fragments (quad lanes at same l15 share a 64B line)
    const u16* vrow[4];
#pragma unroll
    for (int ct = 0; ct < 4; ct++)
        vrow[ct] = vbase + (size_t)(64 * dc + 16 * ct + l15) * SS + quad * 8;

    for (int half = 0; half < 2; half++) {
        const int qt = half ? pr : (31 - pr);   // heavy tile first; pair sums to 70 phases
        const int q0 = qt * 128;
        const int KT = 2 * qt + 2;
        const u16* qbase = qg + ((size_t)b * SS + q0) * EE;
        __syncthreads();   // prior half fully done with all LDS regions
        if (tid < 128) lsum[tid] = 0.f;
        gload16(kptr, (void*)&lds[16640 + tid * 8]);   // K tile 0 -> lk[0]
        bf16x8 qf[2][2];
#pragma unroll
        for (int ct = 0; ct < 2; ct++) {
            int qv = 32 * qc + 16 * ct + l15;
#pragma unroll
            for (int es = 0; es < 2; es++)
                qf[ct][es] = *(const bf16x8*)(qbase + (size_t)qv * EE + es * 32 + quad * 8);
        }
        f32x4 o[4][4];
#pragma unroll
        for (int i = 0; i < 4; i++)
#pragma unroll
            for (int j = 0; j < 4; j++) o[i][j] = f32x4{0.f, 0.f, 0.f, 0.f};
        float rl[2] = {0.f, 0.f};
        __syncthreads();   // prologue staging drained, lsum zeros visible

        for (int p = 0; p <= KT; p++) {
            // ---- issue ks=0 V fragments for pass B(p-1) (L2 loads; 16 regs live) ----
            bf16x8 vbt[4];
            if (p >= 1) {
                const int k0b = (p - 1) * 64;
#pragma unroll
                for (int ct = 0; ct < 4; ct++)
                    vbt[ct] = *(const bf16x8*)(vrow[ct] + k0b);
            }
            // ---- K prefetch for tile p+1 (LDS-DMA, alt slot; drained at phase barrier)
            if (p + 1 < KT)
                gload16(kptr + (size_t)(p + 1) * 64 * EE,
                        (void*)&lds[16640 + ((p + 1) & 1) * 4096 + tid * 8]);
            // ---- pass A(p): S^T (64k x 128q), exp2, P -> lp[p&1] ----
            if (p < KT) {
                const int k0 = p * 64;
                const u16* lk = &lds[16640 + (p & 1) * 4096];
                u16* lpw = &lds[(p & 1) * 8192];
                const bool dg = (p >= KT - 2);
#pragma unroll
                for (int rt = 0; rt < 2; rt++) {
                    int m = 32 * kr + 16 * rt + l15;
                    bf16x8 ka0 = *(const bf16x8*)&lk[m * 64 + ((quad ^ (m & 7))) * 8];
                    bf16x8 ka1 = *(const bf16x8*)&lk[m * 64 + (((4 + quad) ^ (m & 7))) * 8];
#pragma unroll
                    for (int ct = 0; ct < 2; ct++) {
                        f32x4 c = f32x4{0.f, 0.f, 0.f, 0.f};
                        c = MFMA(ka0, qf[ct][0], c);
                        c = MFMA(ka1, qf[ct][1], c);
                        int qv = 32 * qc + 16 * ct + l15;
                        float pv[4];
#pragma unroll
                        for (int r = 0; r < 4; r++) {
                            float arg = __builtin_fmaf(c[r], SCALE2, -MFIX);
                            if (dg) {
                                int kp = k0 + 32 * kr + 16 * rt + 4 * quad + r;
                                if (kp > q0 + qv) arg = -3.0e38f;   // exp2 -> 0
                            }
                            pv[r] = fexp2(arg);
                        }
                        rl[ct] += (pv[0] + pv[1]) + (pv[2] + pv[3]);
                        int g16 = 4 * kr + 2 * rt + (quad >> 1);
                        uint2 pkk;
                        pkk.x = pk2(pv[0], pv[1]);
                        pkk.y = pk2(pv[2], pv[3]);
                        *(uint2*)&lpw[qv * 64 + (g16 ^ (qv & 7)) * 8 + (quad & 1) * 4] = pkk;
                    }
                }
            }
            // ---- pass B(p-1): O += P * Vt ; P from lp[(p-1)&1] ----
            if (p >= 1) {
                const int k0b = (p - 1) * 64;
                const u16* lpr = &lds[((p - 1) & 1) * 8192];
                // issue ks=1 V loads now; covered by ks=0's pa reads + 16 MFMAs
                bf16x8 vb1[4];
#pragma unroll
                for (int ct = 0; ct < 4; ct++)
                    vb1[ct] = *(const bf16x8*)(vrow[ct] + k0b + 32);
                bf16x8 pa[4];
#pragma unroll
                for (int rt = 0; rt < 4; rt++) {
                    int m = 64 * qr + 16 * rt + l15;
                    pa[rt] = *(const bf16x8*)&lpr[m * 64 + ((quad ^ (m & 7))) * 8];
                }
                __builtin_amdgcn_s_setprio(1);
#pragma unroll
                for (int rt = 0; rt < 4; rt++)
#pragma unroll
                    for (int ct = 0; ct < 4; ct++)
                        o[rt][ct] = MFMA(pa[rt], vbt[ct], o[rt][ct]);
                __builtin_amdgcn_s_setprio(0);
#pragma unroll
                for (int rt = 0; rt < 4; rt++) {
                    int m = 64 * qr + 16 * rt + l15;
                    pa[rt] = *(const bf16x8*)&lpr[m * 64 + (((4 + quad) ^ (m & 7))) * 8];
                }
                __builtin_amdgcn_s_setprio(1);
#pragma unroll
                for (int rt = 0; rt < 4; rt++)
#pragma unroll
                    for (int ct = 0; ct < 4; ct++)
                        o[rt][ct] = MFMA(pa[rt], vb1[ct], o[rt][ct]);
                __builtin_amdgcn_s_setprio(0);
            }
            __syncthreads();   // single barrier per phase
        }
        // ---- denominator ----
#pragma unroll
        for (int ct = 0; ct < 2; ct++) {
            float t = rl[ct];
            t += __shfl_xor(t, 16, 64);
            t += __shfl_xor(t, 32, 64);
            if (quad == 0) atomicAdd(&lsum[32 * qc + 16 * ct + l15], t);
        }
        __syncthreads();
        // ---- epilogue ----
        float* obase = out + ((size_t)b * SS + q0) * DD + d0 + dc * 64;
#pragma unroll
        for (int rt = 0; rt < 4; rt++) {
#pragma unroll
            for (int r = 0; r < 4; r++) {
                int row = 64 * qr + 16 * rt + 4 * quad + r;
                float li = 1.0f / lsum[row];
#pragma unroll
                for (int ct = 0; ct < 4; ct++)
                    obase[(size_t)row * DD + ct * 16 + l15] = o[rt][ct][r] * li;
            }
        }
    }
}

extern "C" void kernel_launch(void* const* d_in, const int* in_sizes, int n_in,
                              void* d_out, int out_size, void* d_ws, size_t ws_size,
                              hipStream_t stream) {
    (void)in_sizes; (void)n_in; (void)out_size; (void)ws_size;
    const float* enc = (const float*)d_in[0];
    const float* wq = (const float*)d_in[1];
    const float* wk = (const float*)d_in[2];
    char* ws = (char*)d_ws;
    u16* qbf = (u16*)ws;                  // 2 MiB
    u16* kbf = (u16*)(ws + (2ull << 20)); // 2 MiB
    u16* vt  = (u16*)(ws + (4ull << 20)); // 32 MiB
    float* out = (float*)d_out;

    hipLaunchKernelGGL(k_prep, dim3(256), dim3(512), 0, stream, enc, wq, wk, qbf, kbf, vt);
    hipLaunchKernelGGL(k_attn, dim3(256), dim3(512), 0, stream, qbf, kbf, vt, out);
}

// Round 9
// 238.194 us; speedup vs baseline: 2.8633x; 1.1781x over previous
//
#include <hip/hip_runtime.h>

typedef __bf16 bf16;
typedef bf16 bf16x2 __attribute__((ext_vector_type(2)));
typedef bf16 bf16x8 __attribute__((ext_vector_type(8)));
typedef float f32x4 __attribute__((ext_vector_type(4)));
typedef unsigned int u32;
typedef unsigned short u16;

#define BB 4
#define SS 4096
#define DD 1024
#define EE 64
static constexpr float SCALE2 = 0.18033688011112042f; // (1/8)*log2(e)
static constexpr float MFIX = 16.0f;                  // fixed softmax shift (log2 domain)

#define MFMA(a,b,c) __builtin_amdgcn_mfma_f32_16x16x32_bf16((a),(b),(c),0,0,0)

typedef __attribute__((address_space(3))) unsigned int lds_u32;
typedef const __attribute__((address_space(1))) unsigned int glb_u32;

static __device__ __forceinline__ void gload16(const void* g, void* l) {
    __builtin_amdgcn_global_load_lds((glb_u32*)g, (lds_u32*)l, 16, 0, 0);
}

static __device__ __forceinline__ u16 f2bf(float x) {
    union { bf16 h; u16 u; } v; v.h = (bf16)x;
    return v.u;
}
static __device__ __forceinline__ u32 pk2(float a, float b) {
    bf16x2 t; t[0] = (bf16)a; t[1] = (bf16)b;
    return __builtin_bit_cast(u32, t);
}
static __device__ __forceinline__ float fexp2(float x) {
    return __builtin_amdgcn_exp2f(x);
}

// ---------------- Kernel 1: SINGLE-PASS prep (unchanged — verified) ----------
__global__ __launch_bounds__(512, 2) void k_prep(const float* __restrict__ enc,
                                                 const float* __restrict__ wq,
                                                 const float* __restrict__ wk,
                                                 u16* __restrict__ qout,
                                                 u16* __restrict__ kout,
                                                 u16* __restrict__ vt) {
    __shared__ __align__(16) u16 la[4096];
    __shared__ __align__(16) u16 lw[8192];
    __shared__ __align__(16) u32 lt[2144];
    const int tid = threadIdx.x;
    const int m0 = blockIdx.x * 64;
    const int bb = m0 >> 12, s0 = m0 & 4095;
    const int w = tid >> 6, lane = tid & 63, l15 = lane & 15, quad = lane >> 4;
    const int ari = tid >> 3, ag = tid & 7;
    const int wri = tid >> 2, wg = (tid & 3) * 2;
    const float* arow = enc + (size_t)(m0 + ari) * DD + ag * 8;
    const float* wrow = ((wri < 64) ? (wq + (size_t)wri * DD) : (wk + (size_t)(wri - 64) * DD)) + (tid & 3) * 16;
    const int tdp = tid >> 3, toct = tid & 7;
    u16* vdst = vt + ((size_t)(bb * DD + 2 * tdp)) * SS + s0 + toct * 8;

    float4 a0 = *(const float4*)(arow);
    float4 a1 = *(const float4*)(arow + 4);
    float4 b0 = *(const float4*)(wrow);
    float4 b1 = *(const float4*)(wrow + 4);
    float4 b2 = *(const float4*)(wrow + 8);
    float4 b3 = *(const float4*)(wrow + 12);

    f32x4 acc[4];
#pragma unroll
    for (int i = 0; i < 4; i++) acc[i] = f32x4{0.f, 0.f, 0.f, 0.f};

    for (int kk = 0; kk < DD; kk += 64) {
        uint4 pa, pw0, pw1;
        pa.x = pk2(a0.x, a0.y); pa.y = pk2(a0.z, a0.w);
        pa.z = pk2(a1.x, a1.y); pa.w = pk2(a1.z, a1.w);
        pw0.x = pk2(b0.x, b0.y); pw0.y = pk2(b0.z, b0.w);
        pw0.z = pk2(b1.x, b1.y); pw0.w = pk2(b1.z, b1.w);
        pw1.x = pk2(b2.x, b2.y); pw1.y = pk2(b2.z, b2.w);
        pw1.z = pk2(b3.x, b3.y); pw1.w = pk2(b3.z, b3.w);
        __syncthreads();
        *(uint4*)&la[ari * 64 + (ag ^ (ari & 7)) * 8] = pa;
        *(uint4*)&lw[wri * 64 + ((wg + 0) ^ (wri & 7)) * 8] = pw0;
        *(uint4*)&lw[wri * 64 + ((wg + 1) ^ (wri & 7)) * 8] = pw1;
        lt[(ag * 4 + 0) * 67 + ari] = pa.x;
        lt[(ag * 4 + 1) * 67 + ari] = pa.y;
        lt[(ag * 4 + 2) * 67 + ari] = pa.z;
        lt[(ag * 4 + 3) * 67 + ari] = pa.w;
        __syncthreads();
        if (kk + 64 < DD) {
            a0 = *(const float4*)(arow + kk + 64);
            a1 = *(const float4*)(arow + kk + 68);
            b0 = *(const float4*)(wrow + kk + 64);
            b1 = *(const float4*)(wrow + kk + 68);
            b2 = *(const float4*)(wrow + kk + 72);
            b3 = *(const float4*)(wrow + kk + 76);
        }
        int m = 16 * (w & 3) + l15;
#pragma unroll
        for (int es = 0; es < 2; es++) {
            bf16x8 af = *(const bf16x8*)&la[m * 64 + ((((es << 2) + quad) ^ (m & 7))) * 8];
#pragma unroll
            for (int ct = 0; ct < 4; ct++) {
                int n = 64 * (w >> 2) + 16 * ct + l15;
                bf16x8 bf_ = *(const bf16x8*)&lw[n * 64 + ((((es << 2) + quad) ^ (n & 7))) * 8];
                acc[ct] = MFMA(af, bf_, acc[ct]);
            }
        }
        if (tid < 256) {
            u32 a_[8];
#pragma unroll
            for (int j = 0; j < 8; j++) a_[j] = lt[tdp * 67 + toct * 8 + j];
            uint4 r0, r1;
            r0.x = (a_[0] & 0xffffu) | (a_[1] << 16);
            r0.y = (a_[2] & 0xffffu) | (a_[3] << 16);
            r0.z = (a_[4] & 0xffffu) | (a_[5] << 16);
            r0.w = (a_[6] & 0xffffu) | (a_[7] << 16);
            r1.x = (a_[0] >> 16) | (a_[1] & 0xffff0000u);
            r1.y = (a_[2] >> 16) | (a_[3] & 0xffff0000u);
            r1.z = (a_[4] >> 16) | (a_[5] & 0xffff0000u);
            r1.w = (a_[6] >> 16) | (a_[7] & 0xffff0000u);
            u16* dst = vdst + (size_t)kk * SS;
            *(uint4*)dst = r0;
            *(uint4*)(dst + SS) = r1;
        }
    }
#pragma unroll
    for (int ct = 0; ct < 4; ct++) {
        int n = 64 * (w >> 2) + 16 * ct + l15;
        u16* dst = (n < 64) ? qout : kout;
        int col = n & 63;
#pragma unroll
        for (int r = 0; r < 4; r++) {
            int grow = m0 + 16 * (w & 3) + 4 * quad + r;
            dst[(size_t)grow * EE + col] = f2bf(acc[ct][r]);
        }
    }
}

// ---------------- Kernel 2: attention v4 -- q128, V via DMA triple-buffer -----------
// R7 post-mortem: occupancy is reg-capped at 2 waves/SIMD (120 VGPR + 64 AGPR acc ~
// 184/wave); direct-L2 V loads were latency-exposed at that TLP -> 179us. R0's reg
// round-trip hid the latency but paid gv-load + vmcnt-wait + 4xb128 commit per thread
// per phase. v4 keeps R0's LDS read path for V but stages it with global_load_lds DMA,
// TRIPLE-buffered: DMA for tile p+1 -> lv[(p+1)%3] while pass B reads lv[(p-1)%3]
// (always distinct slots), drained by the phase barrier. No VGPR cost, no commit VALU,
// no mid-phase vmcnt stall. K keeps parity double-buffer. XCD decode retained
// (R7-proven: FETCH 28 MB).
// LDS (u16 idx): lp[2] @0/8192 (16KB ea); lsum @16384; lk[2] @16640/20736 (8KB ea);
//                lv[3] @24832/33024/41216 (32KB ea). Total 147968 B -> 1 block/CU.
__global__ __launch_bounds__(512, 2) void k_attn(const u16* __restrict__ qg, const u16* __restrict__ kg,
                                                 const u16* __restrict__ vt, float* __restrict__ out) {
    __shared__ __align__(16) u16 lds[73984];   // 147968 B
    float* lsum = (float*)&lds[16384];
    const int tid = threadIdx.x;
    const int w = tid >> 6, lane = tid & 63, l15 = lane & 15, quad = lane >> 4;
    // XCD-aware decode (R4/R7-proven): 256 blocks, phys round-robin over 8 XCDs.
    const int xcd = blockIdx.x & 7;
    const int idx = blockIdx.x >> 3;            // [0,32)
    const int pr = idx & 15;                    // q-tile pair selector
    const int combo = xcd * 2 + (idx >> 4);     // [0,16): 2 combos per XCD
    const int ds = combo & 3, b = combo >> 2;
    const int d0 = ds * 256;
    const int kr = w & 1, qc = w >> 1;   // pass A: 2 k-halves x 4 q-slices(32)
    const int dc = w & 3, qr = w >> 2;   // pass B: 4 d-slices(64) x 2 q-halves(64)
    const u16* kbase = kg + (size_t)b * SS * EE;
    const u16* vbase = vt + ((size_t)b * DD + d0) * SS;
    const int kgrow = tid >> 3, kglog = (tid & 7) ^ (kgrow & 7);
    const u16* kptr = kbase + (size_t)kgrow * EE + kglog * 8;
    // pre-swizzled V global sources (R0 layout: DMA writes linearly, reads are XOR'd)
    const u16 *vptr0, *vptr1, *vptr2, *vptr3;
    {
        int go0 = 0 * 512 + tid, gr0 = go0 >> 3, gl0 = (go0 & 7) ^ (gr0 & 7);
        int go1 = 1 * 512 + tid, gr1 = go1 >> 3, gl1 = (go1 & 7) ^ (gr1 & 7);
        int go2 = 2 * 512 + tid, gr2 = go2 >> 3, gl2 = (go2 & 7) ^ (gr2 & 7);
        int go3 = 3 * 512 + tid, gr3 = go3 >> 3, gl3 = (go3 & 7) ^ (gr3 & 7);
        vptr0 = vbase + (size_t)gr0 * SS + gl0 * 8;
        vptr1 = vbase + (size_t)gr1 * SS + gl1 * 8;
        vptr2 = vbase + (size_t)gr2 * SS + gl2 * 8;
        vptr3 = vbase + (size_t)gr3 * SS + gl3 * 8;
    }

    for (int half = 0; half < 2; half++) {
        const int qt = half ? pr : (31 - pr);   // heavy tile first
        const int q0 = qt * 128;
        const int KT = 2 * qt + 2;
        const u16* qbase = qg + ((size_t)b * SS + q0) * EE;
        __syncthreads();   // prior half fully done with all LDS regions
        if (tid < 128) lsum[tid] = 0.f;
        // prologue: K(0)->lk[0], V(0)->lv[0] via LDS-DMA (drained at barrier below)
        gload16(kptr, (void*)&lds[16640 + tid * 8]);
        gload16(vptr0, (void*)&lds[24832 + (0 * 512 + tid) * 8]);
        gload16(vptr1, (void*)&lds[24832 + (1 * 512 + tid) * 8]);
        gload16(vptr2, (void*)&lds[24832 + (2 * 512 + tid) * 8]);
        gload16(vptr3, (void*)&lds[24832 + (3 * 512 + tid) * 8]);
        // Q fragments straight from global (L2-hit)
        bf16x8 qf[2][2];
#pragma unroll
        for (int ct = 0; ct < 2; ct++) {
            int qv = 32 * qc + 16 * ct + l15;
#pragma unroll
            for (int es = 0; es < 2; es++)
                qf[ct][es] = *(const bf16x8*)(qbase + (size_t)qv * EE + es * 32 + quad * 8);
        }
        f32x4 o[4][4];
#pragma unroll
        for (int i = 0; i < 4; i++)
#pragma unroll
            for (int j = 0; j < 4; j++) o[i][j] = f32x4{0.f, 0.f, 0.f, 0.f};
        float rl[2] = {0.f, 0.f};
        __syncthreads();   // prologue staging drained, lsum zeros visible

        int sprv = 2, scur = 0, snxt = 1;   // lv slot rotation: (p-1)%3, p%3, (p+1)%3
        for (int p = 0; p <= KT; p++) {
            // ---- issue DMA for tile p+1: K -> lk[(p+1)&1], V -> lv[snxt] ----
            if (p + 1 < KT) {
                const int k1 = (p + 1) * 64;
                gload16(kptr + (size_t)k1 * EE,
                        (void*)&lds[16640 + ((p + 1) & 1) * 4096 + tid * 8]);
                u16* nv = &lds[24832 + snxt * 16384];
                gload16(vptr0 + k1, (void*)&nv[(0 * 512 + tid) * 8]);
                gload16(vptr1 + k1, (void*)&nv[(1 * 512 + tid) * 8]);
                gload16(vptr2 + k1, (void*)&nv[(2 * 512 + tid) * 8]);
                gload16(vptr3 + k1, (void*)&nv[(3 * 512 + tid) * 8]);
            }
            // ---- pass A(p): S^T (64k x 128q), exp2, P -> lp[p&1] ----
            if (p < KT) {
                const int k0 = p * 64;
                const u16* lk = &lds[16640 + (p & 1) * 4096];
                u16* lpw = &lds[(p & 1) * 8192];
                const bool dg = (p >= KT - 2);
#pragma unroll
                for (int rt = 0; rt < 2; rt++) {
                    int m = 32 * kr + 16 * rt + l15;
                    bf16x8 ka0 = *(const bf16x8*)&lk[m * 64 + ((quad ^ (m & 7))) * 8];
                    bf16x8 ka1 = *(const bf16x8*)&lk[m * 64 + (((4 + quad) ^ (m & 7))) * 8];
#pragma unroll
                    for (int ct = 0; ct < 2; ct++) {
                        f32x4 c = f32x4{0.f, 0.f, 0.f, 0.f};
                        c = MFMA(ka0, qf[ct][0], c);
                        c = MFMA(ka1, qf[ct][1], c);
                        int qv = 32 * qc + 16 * ct + l15;
                        float pv[4];
#pragma unroll
                        for (int r = 0; r < 4; r++) {
                            float arg = __builtin_fmaf(c[r], SCALE2, -MFIX);
                            if (dg) {
                                int kp = k0 + 32 * kr + 16 * rt + 4 * quad + r;
                                if (kp > q0 + qv) arg = -3.0e38f;   // exp2 -> 0
                            }
                            pv[r] = fexp2(arg);
                        }
                        rl[ct] += (pv[0] + pv[1]) + (pv[2] + pv[3]);
                        int g16 = 4 * kr + 2 * rt + (quad >> 1);
                        uint2 pkk;
                        pkk.x = pk2(pv[0], pv[1]);
                        pkk.y = pk2(pv[2], pv[3]);
                        *(uint2*)&lpw[qv * 64 + (g16 ^ (qv & 7)) * 8 + (quad & 1) * 4] = pkk;
                    }
                }
            }
            // ---- pass B(p-1): O += P * Vt from lp[(p-1)&1] / lv[sprv] ----
            if (p >= 1) {
                const u16* lv = &lds[24832 + sprv * 16384];
                const u16* lpr = &lds[((p - 1) & 1) * 8192];
#pragma unroll
                for (int ks = 0; ks < 2; ks++) {
                    bf16x8 vb[4];
#pragma unroll
                    for (int ct = 0; ct < 4; ct++) {
                        int n = 64 * dc + 16 * ct + l15;
                        vb[ct] = *(const bf16x8*)&lv[n * 64 + ((((ks << 2) + quad) ^ (n & 7))) * 8];
                    }
                    bf16x8 pa[4];
#pragma unroll
                    for (int rt = 0; rt < 4; rt++) {
                        int m = 64 * qr + 16 * rt + l15;
                        pa[rt] = *(const bf16x8*)&lpr[m * 64 + ((((ks << 2) + quad) ^ (m & 7))) * 8];
                    }
                    __builtin_amdgcn_s_setprio(1);
#pragma unroll
                    for (int rt = 0; rt < 4; rt++)
#pragma unroll
                        for (int ct = 0; ct < 4; ct++)
                            o[rt][ct] = MFMA(pa[rt], vb[ct], o[rt][ct]);
                    __builtin_amdgcn_s_setprio(0);
                }
            }
            __syncthreads();   // single barrier per phase (drains DMA queue too)
            int t_ = sprv; sprv = scur; scur = snxt; snxt = t_;
        }
        // ---- denominator ----
#pragma unroll
        for (int ct = 0; ct < 2; ct++) {
            float t = rl[ct];
            t += __shfl_xor(t, 16, 64);
            t += __shfl_xor(t, 32, 64);
            if (quad == 0) atomicAdd(&lsum[32 * qc + 16 * ct + l15], t);
        }
        __syncthreads();
        // ---- epilogue ----
        float* obase = out + ((size_t)b * SS + q0) * DD + d0 + dc * 64;
#pragma unroll
        for (int rt = 0; rt < 4; rt++) {
#pragma unroll
            for (int r = 0; r < 4; r++) {
                int row = 64 * qr + 16 * rt + 4 * quad + r;
                float li = 1.0f / lsum[row];
#pragma unroll
                for (int ct = 0; ct < 4; ct++)
                    obase[(size_t)row * DD + ct * 16 + l15] = o[rt][ct][r] * li;
            }
        }
    }
}

extern "C" void kernel_launch(void* const* d_in, const int* in_sizes, int n_in,
                              void* d_out, int out_size, void* d_ws, size_t ws_size,
                              hipStream_t stream) {
    (void)in_sizes; (void)n_in; (void)out_size; (void)ws_size;
    const float* enc = (const float*)d_in[0];
    const float* wq = (const float*)d_in[1];
    const float* wk = (const float*)d_in[2];
    char* ws = (char*)d_ws;
    u16* qbf = (u16*)ws;                  // 2 MiB
    u16* kbf = (u16*)(ws + (2ull << 20)); // 2 MiB
    u16* vt  = (u16*)(ws + (4ull << 20)); // 32 MiB
    float* out = (float*)d_out;

    hipLaunchKernelGGL(k_prep, dim3(256), dim3(512), 0, stream, enc, wq, wk, qbf, kbf, vt);
    hipLaunchKernelGGL(k_attn, dim3(256), dim3(512), 0, stream, qbf, kbf, vt, out);
}

// Round 14
// 223.668 us; speedup vs baseline: 3.0493x; 1.0649x over previous
//
#include <hip/hip_runtime.h>

typedef __bf16 bf16;
typedef bf16 bf16x2 __attribute__((ext_vector_type(2)));
typedef bf16 bf16x8 __attribute__((ext_vector_type(8)));
typedef float f32x4 __attribute__((ext_vector_type(4)));
typedef unsigned int u32;
typedef unsigned short u16;

#define BB 4
#define SS 4096
#define DD 1024
#define EE 64
static constexpr float SCALE2 = 0.18033688011112042f; // (1/8)*log2(e)
static constexpr float MFIX = 16.0f;                  // fixed softmax shift (log2 domain)

#define MFMA(a,b,c) __builtin_amdgcn_mfma_f32_16x16x32_bf16((a),(b),(c),0,0,0)

typedef __attribute__((address_space(3))) unsigned int lds_u32;
typedef const __attribute__((address_space(1))) unsigned int glb_u32;

static __device__ __forceinline__ void gload16(const void* g, void* l) {
    __builtin_amdgcn_global_load_lds((glb_u32*)g, (lds_u32*)l, 16, 0, 0);
}

static __device__ __forceinline__ u16 f2bf(float x) {
    union { bf16 h; u16 u; } v; v.h = (bf16)x;
    return v.u;
}
static __device__ __forceinline__ u32 pk2(float a, float b) {
    bf16x2 t; t[0] = (bf16)a; t[1] = (bf16)b;
    return __builtin_bit_cast(u32, t);
}
static __device__ __forceinline__ float fexp2(float x) {
    return __builtin_amdgcn_exp2f(x);
}

// ---------------- Kernel 1: SINGLE-PASS prep (unchanged — verified) ----------
__global__ __launch_bounds__(512, 2) void k_prep(const float* __restrict__ enc,
                                                 const float* __restrict__ wq,
                                                 const float* __restrict__ wk,
                                                 u16* __restrict__ qout,
                                                 u16* __restrict__ kout,
                                                 u16* __restrict__ vt) {
    __shared__ __align__(16) u16 la[4096];
    __shared__ __align__(16) u16 lw[8192];
    __shared__ __align__(16) u32 lt[2144];
    const int tid = threadIdx.x;
    const int m0 = blockIdx.x * 64;
    const int bb = m0 >> 12, s0 = m0 & 4095;
    const int w = tid >> 6, lane = tid & 63, l15 = lane & 15, quad = lane >> 4;
    const int ari = tid >> 3, ag = tid & 7;
    const int wri = tid >> 2, wg = (tid & 3) * 2;
    const float* arow = enc + (size_t)(m0 + ari) * DD + ag * 8;
    const float* wrow = ((wri < 64) ? (wq + (size_t)wri * DD) : (wk + (size_t)(wri - 64) * DD)) + (tid & 3) * 16;
    const int tdp = tid >> 3, toct = tid & 7;
    u16* vdst = vt + ((size_t)(bb * DD + 2 * tdp)) * SS + s0 + toct * 8;

    float4 a0 = *(const float4*)(arow);
    float4 a1 = *(const float4*)(arow + 4);
    float4 b0 = *(const float4*)(wrow);
    float4 b1 = *(const float4*)(wrow + 4);
    float4 b2 = *(const float4*)(wrow + 8);
    float4 b3 = *(const float4*)(wrow + 12);

    f32x4 acc[4];
#pragma unroll
    for (int i = 0; i < 4; i++) acc[i] = f32x4{0.f, 0.f, 0.f, 0.f};

    for (int kk = 0; kk < DD; kk += 64) {
        uint4 pa, pw0, pw1;
        pa.x = pk2(a0.x, a0.y); pa.y = pk2(a0.z, a0.w);
        pa.z = pk2(a1.x, a1.y); pa.w = pk2(a1.z, a1.w);
        pw0.x = pk2(b0.x, b0.y); pw0.y = pk2(b0.z, b0.w);
        pw0.z = pk2(b1.x, b1.y); pw0.w = pk2(b1.z, b1.w);
        pw1.x = pk2(b2.x, b2.y); pw1.y = pk2(b2.z, b2.w);
        pw1.z = pk2(b3.x, b3.y); pw1.w = pk2(b3.z, b3.w);
        __syncthreads();
        *(uint4*)&la[ari * 64 + (ag ^ (ari & 7)) * 8] = pa;
        *(uint4*)&lw[wri * 64 + ((wg + 0) ^ (wri & 7)) * 8] = pw0;
        *(uint4*)&lw[wri * 64 + ((wg + 1) ^ (wri & 7)) * 8] = pw1;
        lt[(ag * 4 + 0) * 67 + ari] = pa.x;
        lt[(ag * 4 + 1) * 67 + ari] = pa.y;
        lt[(ag * 4 + 2) * 67 + ari] = pa.z;
        lt[(ag * 4 + 3) * 67 + ari] = pa.w;
        __syncthreads();
        if (kk + 64 < DD) {
            a0 = *(const float4*)(arow + kk + 64);
            a1 = *(const float4*)(arow + kk + 68);
            b0 = *(const float4*)(wrow + kk + 64);
            b1 = *(const float4*)(wrow + kk + 68);
            b2 = *(const float4*)(wrow + kk + 72);
            b3 = *(const float4*)(wrow + kk + 76);
        }
        int m = 16 * (w & 3) + l15;
#pragma unroll
        for (int es = 0; es < 2; es++) {
            bf16x8 af = *(const bf16x8*)&la[m * 64 + ((((es << 2) + quad) ^ (m & 7))) * 8];
#pragma unroll
            for (int ct = 0; ct < 4; ct++) {
                int n = 64 * (w >> 2) + 16 * ct + l15;
                bf16x8 bf_ = *(const bf16x8*)&lw[n * 64 + ((((es << 2) + quad) ^ (n & 7))) * 8];
                acc[ct] = MFMA(af, bf_, acc[ct]);
            }
        }
        if (tid < 256) {
            u32 a_[8];
#pragma unroll
            for (int j = 0; j < 8; j++) a_[j] = lt[tdp * 67 + toct * 8 + j];
            uint4 r0, r1;
            r0.x = (a_[0] & 0xffffu) | (a_[1] << 16);
            r0.y = (a_[2] & 0xffffu) | (a_[3] << 16);
            r0.z = (a_[4] & 0xffffu) | (a_[5] << 16);
            r0.w = (a_[6] & 0xffffu) | (a_[7] << 16);
            r1.x = (a_[0] >> 16) | (a_[1] & 0xffff0000u);
            r1.y = (a_[2] >> 16) | (a_[3] & 0xffff0000u);
            r1.z = (a_[4] >> 16) | (a_[5] & 0xffff0000u);
            r1.w = (a_[6] >> 16) | (a_[7] & 0xffff0000u);
            u16* dst = vdst + (size_t)kk * SS;
            *(uint4*)dst = r0;
            *(uint4*)(dst + SS) = r1;
        }
    }
#pragma unroll
    for (int ct = 0; ct < 4; ct++) {
        int n = 64 * (w >> 2) + 16 * ct + l15;
        u16* dst = (n < 64) ? qout : kout;
        int col = n & 63;
#pragma unroll
        for (int r = 0; r < 4; r++) {
            int grow = m0 + 16 * (w & 3) + 4 * quad + r;
            dst[(size_t)grow * EE + col] = f2bf(acc[ct][r]);
        }
    }
}

// ---------------- Kernel 2: attention v5 -- q128, 16 waves (4/SIMD), halved acc -----
// R9 post-mortem: three V-staging schemes (reg-roundtrip 130us, direct-L2 179us,
// DMA-3buf 133us) all converge ~130us -> phase skeleton binds, not staging. Cause:
// 2 waves/SIMD lockstep (192 total regs/wave under cap=512/min_waves law) can't hide
// LDS latency + pass A serial chains; >=1800 idle cyc of 4694/phase vs 1552-cyc
// matrix floor. v5: SAME tile (q128 x d256), SAME pipeline (DMA triple-buffer lv[3],
// lk[2], lp[2], XCD decode), but 1024 threads = 16 waves = 4 waves/SIMD; per-wave
// state halved (o[2][4]=32 acc, qf 8, ~117 total regs <= 128 cap via bounds(1024,4)).
// 4 independent streams/SIMD keep the MFMA pipe fed through stalls.
// Assignments: pass A 2 k-halves x 8 q-slices(16); pass B 4 d-slices(64) x 4 q-qtrs(32).
// LDS (u16 idx): lp[2] @0/8192; lsum @16384; lk[2] @16640/20736; lv[3] @24832+.
__global__ __launch_bounds__(1024, 4) void k_attn(const u16* __restrict__ qg, const u16* __restrict__ kg,
                                                  const u16* __restrict__ vt, float* __restrict__ out) {
    __shared__ __align__(16) u16 lds[73984];   // 147968 B -> 1 block/CU
    float* lsum = (float*)&lds[16384];
    const int tid = threadIdx.x;
    const int w = tid >> 6, lane = tid & 63, l15 = lane & 15, quad = lane >> 4;
    // XCD-aware decode (R4/R7/R9-proven: FETCH ~28MB): 256 blocks, round-robin XCDs.
    const int xcd = blockIdx.x & 7;
    const int idx = blockIdx.x >> 3;            // [0,32)
    const int pr = idx & 15;                    // q-tile pair selector
    const int combo = xcd * 2 + (idx >> 4);     // [0,16): 2 combos per XCD
    const int ds = combo & 3, b = combo >> 2;
    const int d0 = ds * 256;
    const int kr = w & 1, qc = w >> 1;   // pass A: 2 k-halves x 8 q-slices(16)
    const int dc = w & 3, qr = w >> 2;   // pass B: 4 d-slices(64) x 4 q-quarters(32)
    const u16* kbase = kg + (size_t)b * SS * EE;
    const u16* vbase = vt + ((size_t)b * DD + d0) * SS;
    const int kgrow = tid >> 3, kglog = (tid & 7) ^ (kgrow & 7);
    const u16* kptr = kbase + (size_t)kgrow * EE + kglog * 8;   // used by tid<512
    // pre-swizzled V global sources (DMA writes linearly, reads XOR by row&7)
    const u16 *vptr0, *vptr1;
    {
        int go0 = tid,        gr0 = go0 >> 3, gl0 = (go0 & 7) ^ (gr0 & 7);
        int go1 = 1024 + tid, gr1 = go1 >> 3, gl1 = (go1 & 7) ^ (gr1 & 7);
        vptr0 = vbase + (size_t)gr0 * SS + gl0 * 8;
        vptr1 = vbase + (size_t)gr1 * SS + gl1 * 8;
    }

    for (int half = 0; half < 2; half++) {
        const int qt = half ? pr : (31 - pr);   // heavy tile first; pair = 68 phases
        const int q0 = qt * 128;
        const int KT = 2 * qt + 2;
        const u16* qbase = qg + ((size_t)b * SS + q0) * EE;
        __syncthreads();   // prior half fully done with all LDS regions
        if (tid < 128) lsum[tid] = 0.f;
        // prologue: K(0)->lk[0], V(0)->lv[0] via LDS-DMA
        if (tid < 512) gload16(kptr, (void*)&lds[16640 + tid * 8]);
        gload16(vptr0, (void*)&lds[24832 + (0 * 1024 + tid) * 8]);
        gload16(vptr1, (void*)&lds[24832 + (1 * 1024 + tid) * 8]);
        // Q fragments straight from global (L2-hit): 16 q-rows per wave
        bf16x8 qf0, qf1;
        {
            int qv = 16 * qc + l15;
            qf0 = *(const bf16x8*)(qbase + (size_t)qv * EE + quad * 8);
            qf1 = *(const bf16x8*)(qbase + (size_t)qv * EE + 32 + quad * 8);
        }
        f32x4 o[2][4];
#pragma unroll
        for (int i = 0; i < 2; i++)
#pragma unroll
            for (int j = 0; j < 4; j++) o[i][j] = f32x4{0.f, 0.f, 0.f, 0.f};
        float rl = 0.f;
        __syncthreads();   // prologue staging drained, lsum zeros visible

        int sprv = 2, scur = 0, snxt = 1;   // lv slot rotation
        for (int p = 0; p <= KT; p++) {
            // ---- issue DMA for tile p+1: K -> lk[(p+1)&1], V -> lv[snxt] ----
            if (p + 1 < KT) {
                const int k1 = (p + 1) * 64;
                if (tid < 512)
                    gload16(kptr + (size_t)k1 * EE,
                            (void*)&lds[16640 + ((p + 1) & 1) * 4096 + tid * 8]);
                u16* nv = &lds[24832 + snxt * 16384];
                gload16(vptr0 + k1, (void*)&nv[(0 * 1024 + tid) * 8]);
                gload16(vptr1 + k1, (void*)&nv[(1 * 1024 + tid) * 8]);
            }
            // ---- pass A(p): S^T (64k x 128q), exp2, P -> lp[p&1] ----
            if (p < KT) {
                const int k0 = p * 64;
                const u16* lk = &lds[16640 + (p & 1) * 4096];
                u16* lpw = &lds[(p & 1) * 8192];
                const bool dg = (p >= KT - 2);
                const int qv = 16 * qc + l15;
#pragma unroll
                for (int rt = 0; rt < 2; rt++) {
                    int m = 32 * kr + 16 * rt + l15;
                    bf16x8 ka0 = *(const bf16x8*)&lk[m * 64 + ((quad ^ (m & 7))) * 8];
                    bf16x8 ka1 = *(const bf16x8*)&lk[m * 64 + (((4 + quad) ^ (m & 7))) * 8];
                    f32x4 c = f32x4{0.f, 0.f, 0.f, 0.f};
                    c = MFMA(ka0, qf0, c);
                    c = MFMA(ka1, qf1, c);
                    float pv[4];
#pragma unroll
                    for (int r = 0; r < 4; r++) {
                        float arg = __builtin_fmaf(c[r], SCALE2, -MFIX);
                        if (dg) {
                            int kp = k0 + 32 * kr + 16 * rt + 4 * quad + r;
                            if (kp > q0 + qv) arg = -3.0e38f;   // exp2 -> 0
                        }
                        pv[r] = fexp2(arg);
                    }
                    rl += (pv[0] + pv[1]) + (pv[2] + pv[3]);
                    int g16 = 4 * kr + 2 * rt + (quad >> 1);
                    uint2 pkk;
                    pkk.x = pk2(pv[0], pv[1]);
                    pkk.y = pk2(pv[2], pv[3]);
                    *(uint2*)&lpw[qv * 64 + (g16 ^ (qv & 7)) * 8 + (quad & 1) * 4] = pkk;
                }
            }
            // ---- pass B(p-1): O += P * Vt from lp[(p-1)&1] / lv[sprv] ----
            if (p >= 1) {
                const u16* lv = &lds[24832 + sprv * 16384];
                const u16* lpr = &lds[((p - 1) & 1) * 8192];
#pragma unroll
                for (int ks = 0; ks < 2; ks++) {
                    bf16x8 vb[4];
#pragma unroll
                    for (int ct = 0; ct < 4; ct++) {
                        int n = 64 * dc + 16 * ct + l15;
                        vb[ct] = *(const bf16x8*)&lv[n * 64 + ((((ks << 2) + quad) ^ (n & 7))) * 8];
                    }
                    bf16x8 pa[2];
#pragma unroll
                    for (int rt = 0; rt < 2; rt++) {
                        int m = 32 * qr + 16 * rt + l15;
                        pa[rt] = *(const bf16x8*)&lpr[m * 64 + ((((ks << 2) + quad) ^ (m & 7))) * 8];
                    }
                    __builtin_amdgcn_s_setprio(1);
#pragma unroll
                    for (int rt = 0; rt < 2; rt++)
#pragma unroll
                        for (int ct = 0; ct < 4; ct++)
                            o[rt][ct] = MFMA(pa[rt], vb[ct], o[rt][ct]);
                    __builtin_amdgcn_s_setprio(0);
                }
            }
            __syncthreads();   // single barrier per phase (drains DMA queue too)
            int t_ = sprv; sprv = scur; scur = snxt; snxt = t_;
        }
        // ---- denominator ----
        {
            float t = rl;
            t += __shfl_xor(t, 16, 64);
            t += __shfl_xor(t, 32, 64);
            if (quad == 0) atomicAdd(&lsum[16 * qc + l15], t);
        }
        __syncthreads();
        // ---- epilogue ----
        float* obase = out + ((size_t)b * SS + q0) * DD + d0 + dc * 64;
#pragma unroll
        for (int rt = 0; rt < 2; rt++) {
#pragma unroll
            for (int r = 0; r < 4; r++) {
                int row = 32 * qr + 16 * rt + 4 * quad + r;
                float li = 1.0f / lsum[row];
#pragma unroll
                for (int ct = 0; ct < 4; ct++)
                    obase[(size_t)row * DD + ct * 16 + l15] = o[rt][ct][r] * li;
            }
        }
    }
}

extern "C" void kernel_launch(void* const* d_in, const int* in_sizes, int n_in,
                              void* d_out, int out_size, void* d_ws, size_t ws_size,
                              hipStream_t stream) {
    (void)in_sizes; (void)n_in; (void)out_size; (void)ws_size;
    const float* enc = (const float*)d_in[0];
    const float* wq = (const float*)d_in[1];
    const float* wk = (const float*)d_in[2];
    char* ws = (char*)d_ws;
    u16* qbf = (u16*)ws;                  // 2 MiB
    u16* kbf = (u16*)(ws + (2ull << 20)); // 2 MiB
    u16* vt  = (u16*)(ws + (4ull << 20)); // 32 MiB
    float* out = (float*)d_out;

    hipLaunchKernelGGL(k_prep, dim3(256), dim3(512), 0, stream, enc, wq, wk, qbf, kbf, vt);
    hipLaunchKernelGGL(k_attn, dim3(256), dim3(1024), 0, stream, qbf, kbf, vt, out);
}